// Round 18
// baseline (165.327 us; speedup 1.0000x reference)
//
#include <hip/hip_runtime.h>
#include <hip/hip_fp16.h>

#define BB 4
#define CC 32
#define HH 480
#define WW 640
#define HWv (HH*WW)

typedef _Float16 half2v __attribute__((ext_vector_type(2)));

union H8 { __half h[8]; float4 f4; };
union H4 { short4 s; __half h[4]; };
union PK { float f; half2v h2; };     // bitcast container for cvt_pkrtz result

__device__ __forceinline__ half2v pack2(float a, float b) {
    PK u;
    u.f = __builtin_bit_cast(float, __builtin_amdgcn_cvt_pkrtz(a, b));
    return u.h2;
}

#if __has_builtin(__builtin_amdgcn_fdot2)
#define FDOT2(a, b, c) __builtin_amdgcn_fdot2((a), (b), (c), false)
#else
#define FDOT2(a, b, c) ((float)(a)[0]*(float)(b)[0] + (float)(a)[1]*(float)(b)[1] + (c))
#endif

// ---------------------------------------------------------------------------
// Kernel 0: pack conv weights into channel-pair half2 table.
// wpk[c2*72 + o*9 + tap] = { Wf[o][2c2][tap], Wf[o][2c2+1][tap] }
// ---------------------------------------------------------------------------
__global__ __launch_bounds__(128) void pack_w(const float* __restrict__ Wf,
                                              half2v* __restrict__ wpk)
{
    for (int i = threadIdx.x; i < (CC / 2) * 8 * 9; i += 128) {
        int c2  = i / 72;
        int rem = i - c2 * 72;
        int o   = rem / 9;
        int tap = rem - o * 9;
        float wa = Wf[(o * CC + 2 * c2) * 9 + tap];
        float wb = Wf[(o * CC + 2 * c2 + 1) * 9 + tap];
        wpk[i] = pack2(wa, wb);
    }
}

// ---------------------------------------------------------------------------
// Kernel 1: 3x3 conv (32->8) + bias + affinity normalization, fused.
// R9 load structure (best measured), compute via v_dot2_f32_f16 on channel
// PAIRS: 2 fp16 MACs/lane/cy with f32 accumulation. Per 2 channels:
// 576 dot2 + 30 cvt_pkrtz vs 1152 v_fma -> ~0.53x VALU work. Weights read
// from the pre-packed half2 table (wave-uniform -> s_load -> SGPR operand).
// Precision: input quantization 4.9e-4 scales with the 288-term sum ->
// aff rel err ~5e-4, same order as fp16-K storage (absmax 256 measured).
// Output: K [B][9][H][W] fp16, K[0] = 1 - sum(a), K[1..8] = aff_k / sum|aff|
// ---------------------------------------------------------------------------
__global__ __launch_bounds__(128) void conv_gen(const float* __restrict__ kx,
                                                const half2v* __restrict__ wpk,
                                                const float* __restrict__ bf,
                                                __half* __restrict__ K)
{
    int tid = blockIdx.x * 128 + threadIdx.x;
    const int XT = WW / 8;              // 80 thread-columns
    int x8 = tid % XT;
    int t2 = tid / XT;
    int y  = t2 % HH;
    int b  = t2 / HH;
    if (b >= BB) return;
    int x0 = x8 * 8;

    float acc[8][8];
#pragma unroll
    for (int o = 0; o < 8; ++o) {
        float bv = bf[o];
#pragma unroll
        for (int p = 0; p < 8; ++p) acc[o][p] = bv;
    }

    const float* kxb = kx + (size_t)b * CC * HWv + (size_t)y * WW + x0;
    const bool xm = (x0 > 0);
    const bool xp = (x0 + 8 < WW);

#pragma unroll 1
    for (int c2 = 0; c2 < CC / 2; ++c2) {
        const float* plA = kxb + (size_t)(2 * c2)     * HWv;
        const float* plB = kxb + (size_t)(2 * c2 + 1) * HWv;

        // ---- R9-style branchy row loads for both channels of the pair ----
        float rowA[3][10], rowB[3][10];
#pragma unroll
        for (int r = 0; r < 3; ++r) {
            const int dy = r - 1;
            const bool rowok = (y + dy >= 0) && (y + dy < HH);
            const float* rpA = plA + dy * WW;
            const float* rpB = plB + dy * WW;
            if (rowok) {
                float4 a0 = *reinterpret_cast<const float4*>(rpA);
                float4 a1 = *reinterpret_cast<const float4*>(rpA + 4);
                rowA[r][0] = xm ? rpA[-1] : 0.f;
                rowA[r][1] = a0.x; rowA[r][2] = a0.y; rowA[r][3] = a0.z; rowA[r][4] = a0.w;
                rowA[r][5] = a1.x; rowA[r][6] = a1.y; rowA[r][7] = a1.z; rowA[r][8] = a1.w;
                rowA[r][9] = xp ? rpA[8] : 0.f;
                float4 b0 = *reinterpret_cast<const float4*>(rpB);
                float4 b1 = *reinterpret_cast<const float4*>(rpB + 4);
                rowB[r][0] = xm ? rpB[-1] : 0.f;
                rowB[r][1] = b0.x; rowB[r][2] = b0.y; rowB[r][3] = b0.z; rowB[r][4] = b0.w;
                rowB[r][5] = b1.x; rowB[r][6] = b1.y; rowB[r][7] = b1.z; rowB[r][8] = b1.w;
                rowB[r][9] = xp ? rpB[8] : 0.f;
            } else {
#pragma unroll
                for (int q = 0; q < 10; ++q) { rowA[r][q] = 0.f; rowB[r][q] = 0.f; }
            }
        }

        // ---- pack channel pairs: row2[r][q] = {xA, xB} ----
        half2v row2[3][10];
#pragma unroll
        for (int r = 0; r < 3; ++r)
#pragma unroll
            for (int q = 0; q < 10; ++q)
                row2[r][q] = pack2(rowA[r][q], rowB[r][q]);

        // ---- 576 dot2 (wave-uniform packed weights -> SGPR operand) ----
        const half2v* wc = wpk + c2 * 72;
#pragma unroll
        for (int o = 0; o < 8; ++o) {
#pragma unroll
            for (int r = 0; r < 3; ++r) {
#pragma unroll
                for (int t = 0; t < 3; ++t) {
                    half2v w2 = wc[o * 9 + r * 3 + t];
#pragma unroll
                    for (int p = 0; p < 8; ++p)
                        acc[o][p] = FDOT2(row2[r][p + t], w2, acc[o][p]);
                }
            }
        }
    }

    // ---- normalization: a = aff / sum|aff|; K0 = 1 - sum(a) ----
    float k0[8];
#pragma unroll
    for (int p = 0; p < 8; ++p) {
        float asum = 0.f;
#pragma unroll
        for (int o = 0; o < 8; ++o) asum += fabsf(acc[o][p]);
        float rinv = 1.0f / asum;
        float s = 0.f;
#pragma unroll
        for (int o = 0; o < 8; ++o) { acc[o][p] *= rinv; s += acc[o][p]; }
        k0[p] = 1.0f - s;
    }

    size_t base = (size_t)b * 9 * HWv + (size_t)y * WW + x0;
    {
        H8 u;
#pragma unroll
        for (int p = 0; p < 8; ++p) u.h[p] = __float2half(k0[p]);
        *reinterpret_cast<float4*>(K + base) = u.f4;
    }
#pragma unroll
    for (int o = 0; o < 8; ++o) {
        H8 u;
#pragma unroll
        for (int p = 0; p < 8; ++p) u.h[p] = __float2half(acc[o][p]);
        *reinterpret_cast<float4*>(K + base + (size_t)(o + 1) * HWv) = u.f4;
    }
}

// ---------------------------------------------------------------------------
// Kernel 2: one propagation iteration, templated on x dtype (R16-proven).
// Iter 0: f32 -> fp16;  1..10: fp16 -> fp16;  11: fp16 -> f32 d_out.
// OFFSETS order: (0,0),(0,1),(0,-1),(1,0),(1,1),(1,-1),(-1,0),(-1,1),(-1,-1)
// ---------------------------------------------------------------------------
__device__ __forceinline__ void load_row6(const float* r, bool rowok, bool xm,
                                          bool xpl, float o[6])
{
    if (rowok) {
        float4 v = *reinterpret_cast<const float4*>(r);
        o[0] = xm ? r[-1] : 0.f;
        o[1] = v.x; o[2] = v.y; o[3] = v.z; o[4] = v.w;
        o[5] = xpl ? r[4] : 0.f;
    } else {
#pragma unroll
        for (int q = 0; q < 6; ++q) o[q] = 0.f;
    }
}

__device__ __forceinline__ void load_row6h(const __half* r, bool rowok, bool xm,
                                           bool xpl, float o[6])
{
    if (rowok) {
        H4 u;
        u.s = *reinterpret_cast<const short4*>(r);     // 8 B, aligned (x0%4==0)
        o[0] = xm ? __half2float(r[-1]) : 0.f;
        o[1] = __half2float(u.h[0]); o[2] = __half2float(u.h[1]);
        o[3] = __half2float(u.h[2]); o[4] = __half2float(u.h[3]);
        o[5] = xpl ? __half2float(r[4]) : 0.f;
    } else {
#pragma unroll
        for (int q = 0; q < 6; ++q) o[q] = 0.f;
    }
}

template <typename TI, typename TO>
__global__ __launch_bounds__(256) void prop(const TI* __restrict__ xin,
                                            const __half* __restrict__ K,
                                            TO* __restrict__ xout)
{
    int tid = blockIdx.x * 256 + threadIdx.x;
    const int XT = WW / 4;
    int x4 = tid % XT;
    int t2 = tid / XT;
    int y  = t2 % HH;
    int b  = t2 / HH;
    if (b >= BB) return;
    int x0 = x4 * 4;

    const bool xm  = (x0 > 0);
    const bool xpl = (x0 + 4 < WW);

    const TI* xb = xin + (size_t)b * HWv + (size_t)y * WW + x0;
    float rm[6], r0[6], rp[6];
    if constexpr (sizeof(TI) == 4) {
        load_row6((const float*)xb - WW, y > 0,      xm, xpl, rm);
        load_row6((const float*)xb,      true,       xm, xpl, r0);
        load_row6((const float*)xb + WW, y < HH - 1, xm, xpl, rp);
    } else {
        load_row6h((const __half*)xb - WW, y > 0,      xm, xpl, rm);
        load_row6h((const __half*)xb,      true,       xm, xpl, r0);
        load_row6h((const __half*)xb + WW, y < HH - 1, xm, xpl, rp);
    }

    const __half* Kb = K + (size_t)b * 9 * HWv + (size_t)y * WW + x0;
    float kv[9][4];
#pragma unroll
    for (int k = 0; k < 9; ++k) {
        H4 u;
        u.s = *reinterpret_cast<const short4*>(Kb + (size_t)k * HWv);  // 8 B
#pragma unroll
        for (int p = 0; p < 4; ++p) kv[k][p] = __half2float(u.h[p]);
    }

    float o4[4];
#pragma unroll
    for (int p = 0; p < 4; ++p) {
        o4[p] = kv[0][p] * r0[p + 1]
              + kv[1][p] * r0[p]
              + kv[2][p] * r0[p + 2]
              + kv[3][p] * rm[p + 1]
              + kv[4][p] * rm[p]
              + kv[5][p] * rm[p + 2]
              + kv[6][p] * rp[p + 1]
              + kv[7][p] * rp[p]
              + kv[8][p] * rp[p + 2];
    }

    TO* ob = xout + (size_t)b * HWv + (size_t)y * WW + x0;
    if constexpr (sizeof(TO) == 4) {
        *reinterpret_cast<float4*>((float*)ob) =
            make_float4(o4[0], o4[1], o4[2], o4[3]);
    } else {
        H4 u;
#pragma unroll
        for (int p = 0; p < 4; ++p) u.h[p] = __float2half(o4[p]);
        *reinterpret_cast<short4*>((__half*)ob) = u.s;
    }
}

// ---------------------------------------------------------------------------
extern "C" void kernel_launch(void* const* d_in, const int* in_sizes, int n_in,
                              void* d_out, int out_size, void* d_ws, size_t ws_size,
                              hipStream_t stream) {
    const float* kx   = (const float*)d_in[0];   // [4,32,480,640]
    const float* x_in = (const float*)d_in[1];   // [4,1,480,640]
    const float* Wf   = (const float*)d_in[2];   // [8,32,3,3]
    const float* bf   = (const float*)d_in[3];   // [8]
    float* out  = (float*)d_out;                 // [4,1,480,640]

    __half*  Kbuf = (__half*)d_ws;                        // 22.12 MB fp16
    __half*  xh0  = Kbuf + (size_t)9 * BB * HWv;          // 2.46 MB fp16
    __half*  xh1  = xh0  + (size_t)BB * HWv;              // 2.46 MB fp16
    half2v*  wpk  = (half2v*)(xh1 + (size_t)BB * HWv);    // 4.6 KB
    __half*  ping[2] = { xh0, xh1 };

    // weight pack: single tiny block
    pack_w<<<1, 128, 0, stream>>>(Wf, wpk);

    // conv: 8 px/thread, block=128 -> 1200 blocks
    const int cthreads = BB * HH * (WW / 8);      // 153600
    conv_gen<<<cthreads / 128, 128, 0, stream>>>(kx, wpk, bf, Kbuf);

    // prop: 12 launches; intermediates fp16
    const int pblocks = BB * HH * (WW / 4) / 256; // 1200

    prop<float, __half><<<pblocks, 256, 0, stream>>>(x_in, Kbuf, ping[0]);
    for (int it = 1; it <= 10; ++it) {
        prop<__half, __half><<<pblocks, 256, 0, stream>>>(
            ping[(it - 1) & 1], Kbuf, ping[it & 1]);
    }
    prop<__half, float><<<pblocks, 256, 0, stream>>>(ping[0], Kbuf, out);
}